// Round 2
// baseline (610.268 us; speedup 1.0000x reference)
//
#include <hip/hip_runtime.h>
#include <math.h>

#define NROWS 8192   // BATCH*NODE
#define DIM   128
#define FEAT  256
#define KSPLIT 4
#define KCH   (NROWS / KSPLIT)  // 2048

typedef __attribute__((ext_vector_type(8))) __bf16 bf16x8;
typedef __attribute__((ext_vector_type(8))) unsigned short u16x8;
typedef __attribute__((ext_vector_type(4))) float f32x4;

__device__ __forceinline__ float bf2f(unsigned short h) {
  return __uint_as_float(((unsigned)h) << 16);
}
__device__ __forceinline__ unsigned short f2bf(float f) {
  unsigned u = __float_as_uint(f);
  return (unsigned short)((u + 0x7fff + ((u >> 16) & 1)) >> 16);  // RNE
}
__device__ __forceinline__ f32x4 mfma16(bf16x8 a, bf16x8 b, f32x4 c) {
  return __builtin_amdgcn_mfma_f32_16x16x32_bf16(a, b, c, 0, 0, 0);
}

// ---------------------------------------------------------------------------
// dtype detection: if L is f32, even-index shorts are mantissa bits (uniform)
// -> ~25% have bf16-exponent >= 192. If bf16, |L| <= ~0.07 -> exponent < 123.
// ---------------------------------------------------------------------------
__global__ void detect_kernel(const unsigned short* __restrict__ L,
                              int* __restrict__ flag)
{
  __shared__ int cnt;
  if (threadIdx.x == 0) cnt = 0;
  __syncthreads();
  int c = 0;
  for (int i = 0; i < 64; i++) {
    unsigned short s = L[2 * (threadIdx.x + 256 * i)];
    int e = (s >> 7) & 0xFF;
    if (e >= 192) c++;
  }
  atomicAdd(&cnt, c);
  __syncthreads();
  if (threadIdx.x == 0) *flag = (cnt > 16) ? 1 : 0;
}

// ---------------------------------------------------------------------------
// copy-or-convert a tensor to bf16
// ---------------------------------------------------------------------------
__global__ void cvt_tensor(const void* __restrict__ src,
                           unsigned short* __restrict__ dst, int n,
                           const int* __restrict__ flag)
{
  const int is32 = *flag;
  for (int i = blockIdx.x * 256 + threadIdx.x; i < n; i += gridDim.x * 256)
    dst[i] = is32 ? f2bf(((const float*)src)[i])
                  : ((const unsigned short*)src)[i];
}

// params: g0[256] b0[256] w0[32768] bi0[128] g1[256] b1[256] w1[32768] bi1[128]
__global__ void cvt_params(const void* g0, const void* b0, const void* w0,
                           const void* bi0, const void* g1, const void* b1,
                           const void* w1, const void* bi1,
                           unsigned short* __restrict__ dst,
                           const int* __restrict__ flag)
{
  const int is32 = *flag;
  for (int i = blockIdx.x * 256 + threadIdx.x; i < 66816; i += gridDim.x * 256) {
    const void* src; int off;
    if      (i < 256)   { src = g0;  off = i; }
    else if (i < 512)   { src = b0;  off = i - 256; }
    else if (i < 33280) { src = w0;  off = i - 512; }
    else if (i < 33408) { src = bi0; off = i - 33280; }
    else if (i < 33664) { src = g1;  off = i - 33408; }
    else if (i < 33920) { src = b1;  off = i - 33664; }
    else if (i < 66688) { src = w1;  off = i - 33920; }
    else                { src = bi1; off = i - 66688; }
    dst[i] = is32 ? f2bf(((const float*)src)[off])
                  : ((const unsigned short*)src)[off];
  }
}

// ---------------------------------------------------------------------------
// elu(optional) + transpose: src (8192x128 bf16) -> xT (128x8192), xcopy
// ---------------------------------------------------------------------------
__global__ __launch_bounds__(256) void trans_kernel(
    const unsigned short* __restrict__ src, unsigned short* __restrict__ xT,
    unsigned short* __restrict__ xcopy, int do_elu)
{
  __shared__ __align__(16) unsigned short T[128 * 136];  // pad 128->136
  const int tid = threadIdx.x;
  const int r0 = blockIdx.x * 128;
  #pragma unroll
  for (int i = 0; i < 8; i++) {
    const int c = tid + 256 * i;           // 0..2047
    const int rr = c >> 4, cg = c & 15;
    u16x8 v = *(const u16x8*)(src + (size_t)(r0 + rr) * DIM + cg * 8);
    if (do_elu) {
      #pragma unroll
      for (int e = 0; e < 8; e++) {
        float f = bf2f(v[e]);
        f = f > 0.f ? f : expm1f(f);
        v[e] = f2bf(f);
      }
      *(u16x8*)(xcopy + (size_t)(r0 + rr) * DIM + cg * 8) = v;
    }
    *(u16x8*)(T + rr * 136 + cg * 8) = v;
  }
  __syncthreads();
  #pragma unroll
  for (int i = 0; i < 8; i++) {
    const int c = tid + 256 * i;
    const int n = c >> 4, mg = c & 15;
    u16x8 v;
    #pragma unroll
    for (int e = 0; e < 8; e++) v[e] = T[(mg * 8 + e) * 136 + n];
    *(u16x8*)(xT + (size_t)n * NROWS + r0 + mg * 8) = v;
  }
}

// ---------------------------------------------------------------------------
// column stats of bf16 x (features 0..127)
// ---------------------------------------------------------------------------
__global__ void colstats_x(const unsigned short* __restrict__ x,
                           float* __restrict__ stats)
{
  const int col = threadIdx.x;          // 0..127
  const int r0 = blockIdx.x * 64;
  float s = 0.f, q = 0.f;
  for (int i = 0; i < 64; i++) {
    float v = bf2f(x[(size_t)(r0 + i) * DIM + col]);
    s += v; q += v * v;
  }
  atomicAdd(&stats[col], s);
  atomicAdd(&stats[256 + col], q);
}

// ---------------------------------------------------------------------------
// Lx fp32 -> bf16 + column stats (features 128..255)
// ---------------------------------------------------------------------------
__global__ void lx_stats(const float* __restrict__ Lx,
                         unsigned short* __restrict__ Lxb,
                         float* __restrict__ stats)
{
  const int col = threadIdx.x;          // 0..127
  const int r0 = blockIdx.x * 64;
  float s = 0.f, q = 0.f;
  for (int i = 0; i < 64; i++) {
    float v = Lx[(size_t)(r0 + i) * DIM + col];
    Lxb[(size_t)(r0 + i) * DIM + col] = f2bf(v);
    s += v; q += v * v;
  }
  atomicAdd(&stats[128 + col], s);
  atomicAdd(&stats[384 + col], q);
}

// ---------------------------------------------------------------------------
// fold BN into FC
// ---------------------------------------------------------------------------
__global__ void prep_kernel(const float* __restrict__ stats,
                            const unsigned short* __restrict__ gamma,
                            const unsigned short* __restrict__ beta,
                            const unsigned short* __restrict__ w,
                            const unsigned short* __restrict__ bias,
                            unsigned short* __restrict__ weff,
                            float* __restrict__ beff)
{
  const int k = blockIdx.x;   // 0..127
  const int j = threadIdx.x;  // 0..255
  const float inv = 1.f / 8192.f;
  float mu = stats[j] * inv;
  float var = fmaxf(stats[256 + j] * inv - mu * mu, 0.f);
  float s = bf2f(gamma[j]) * rsqrtf(var + 1e-5f);
  float wv = bf2f(w[(size_t)k * FEAT + j]);
  weff[(size_t)k * FEAT + j] = f2bf(wv * s);
  float term = (bf2f(beta[j]) - mu * s) * wv;
  __shared__ float red[256];
  red[j] = term;
  __syncthreads();
  for (int off = 128; off > 0; off >>= 1) {
    if (j < off) red[j] += red[j + off];
    __syncthreads();
  }
  if (j == 0) beff[k] = bf2f(bias[k]) + red[0];
}

// ---------------------------------------------------------------------------
// GEMM1 (split-K): Lx += L[m0:+128, k0:+2048] @ x[k0:+2048, :]
// Conservative staging: register loads + ds_write_b128, plain LDS layout.
// A (=L) is dual-dtype: bf16 or f32 selected by *flag.
// ---------------------------------------------------------------------------
__global__ __launch_bounds__(256) void gemm1_splitk(
    const void* __restrict__ Lraw,           // 8192 x 8192 (bf16 or f32)
    const unsigned short* __restrict__ xT,   // 128 x 8192 bf16
    float* __restrict__ Lx,                  // 8192 x 128 f32 (pre-zeroed)
    const int* __restrict__ flag)
{
  __shared__ __align__(16) unsigned short As[128 * 32];
  __shared__ __align__(16) unsigned short Bs[128 * 32];
  const int is32 = *flag;
  const int tid  = threadIdx.x;
  const int lane = tid & 63;
  const int wave = tid >> 6;
  const int m0 = blockIdx.x * 128;
  const int k0 = blockIdx.y * KCH;

  // this thread stages chunks tid and tid+256 (8 elems each) of A and B
  const int r0s = tid >> 2;          // 0..63
  const int kg  = tid & 3;           // k-group 0..3
  // element offsets (advance +32 per k-tile)
  long eA0 = (long)(m0 + r0s) * NROWS + k0 + kg * 8;
  long eA1 = (long)(m0 + r0s + 64) * NROWS + k0 + kg * 8;
  long eB0 = (long)r0s * NROWS + k0 + kg * 8;
  long eB1 = (long)(r0s + 64) * NROWS + k0 + kg * 8;
  unsigned short* sA0 = As + r0s * 32 + kg * 8;
  unsigned short* sA1 = As + (r0s + 64) * 32 + kg * 8;
  unsigned short* sB0 = Bs + r0s * 32 + kg * 8;
  unsigned short* sB1 = Bs + (r0s + 64) * 32 + kg * 8;

  const int ln = lane & 15, quad = lane >> 4;
  const int mq = (wave & 1) * 64, nq = (wave >> 1) * 64;

  f32x4 acc[4][4];
  #pragma unroll
  for (int i = 0; i < 4; i++)
    #pragma unroll
    for (int j = 0; j < 4; j++)
      acc[i][j] = (f32x4){0.f, 0.f, 0.f, 0.f};

  for (int kb = 0; kb < KCH / 32; ++kb) {
    u16x8 a0, a1, b0, b1;
    if (is32) {
      const float* Lf = (const float*)Lraw;
      f32x4 p0 = *(const f32x4*)(Lf + eA0), p1 = *(const f32x4*)(Lf + eA0 + 4);
      f32x4 q0 = *(const f32x4*)(Lf + eA1), q1 = *(const f32x4*)(Lf + eA1 + 4);
      #pragma unroll
      for (int e = 0; e < 4; e++) {
        a0[e] = f2bf(p0[e]); a0[e + 4] = f2bf(p1[e]);
        a1[e] = f2bf(q0[e]); a1[e + 4] = f2bf(q1[e]);
      }
    } else {
      const unsigned short* Lh = (const unsigned short*)Lraw;
      a0 = *(const u16x8*)(Lh + eA0);
      a1 = *(const u16x8*)(Lh + eA1);
    }
    b0 = *(const u16x8*)(xT + eB0);
    b1 = *(const u16x8*)(xT + eB1);
    eA0 += 32; eA1 += 32; eB0 += 32; eB1 += 32;

    __syncthreads();   // previous iteration's LDS readers done
    *(u16x8*)sA0 = a0;
    *(u16x8*)sA1 = a1;
    *(u16x8*)sB0 = b0;
    *(u16x8*)sB1 = b1;
    __syncthreads();   // staging visible

    bf16x8 af[4], bfr[4];
    #pragma unroll
    for (int i = 0; i < 4; i++)
      af[i] = *(const bf16x8*)(As + (mq + i * 16 + ln) * 32 + quad * 8);
    #pragma unroll
    for (int j = 0; j < 4; j++)
      bfr[j] = *(const bf16x8*)(Bs + (nq + j * 16 + ln) * 32 + quad * 8);
    #pragma unroll
    for (int i = 0; i < 4; i++)
      #pragma unroll
      for (int j = 0; j < 4; j++)
        acc[i][j] = mfma16(af[i], bfr[j], acc[i][j]);
  }

  // fp32 atomic accumulation (KSPLIT contenders per address)
  #pragma unroll
  for (int i = 0; i < 4; i++) {
    const int gmb = m0 + mq + i * 16 + quad * 4;
    #pragma unroll
    for (int j = 0; j < 4; j++) {
      const int gn = nq + j * 16 + ln;
      #pragma unroll
      for (int r = 0; r < 4; r++)
        atomicAdd(&Lx[(size_t)(gmb + r) * DIM + gn], acc[i][j][r]);
    }
  }
}

// ---------------------------------------------------------------------------
// GEMM2: out = [x | Lxb] @ weff.T + beff ; mode0: elu->bf16 x1
// mode1: + resid -> d_out (bf16 or f32 per flag)
// ---------------------------------------------------------------------------
__global__ __launch_bounds__(256) void gemm2_fc(
    const unsigned short* __restrict__ xb,    // 8192x128
    const unsigned short* __restrict__ Lxb,   // 8192x128
    const unsigned short* __restrict__ weff,  // 128x256
    const float* __restrict__ beff,           // 128
    const unsigned short* __restrict__ resid, // inp_c (mode1) or nullptr
    void* __restrict__ outv,
    int mode, const int* __restrict__ flag)
{
  __shared__ __align__(16) unsigned short As[64 * 264];
  const int is32 = *flag;
  const int tid = threadIdx.x;
  const int lane = tid & 63, wave = tid >> 6;
  const int m0 = blockIdx.x * 64;

  #pragma unroll
  for (int i = 0; i < 8; i++) {
    const int c = tid + 256 * i;        // 0..2047 (64 rows x 32 chunks)
    const int mr = c >> 5, ch = c & 31;
    const unsigned short* src =
        (ch < 16) ? (xb  + (size_t)(m0 + mr) * DIM + ch * 8)
                  : (Lxb + (size_t)(m0 + mr) * DIM + (ch - 16) * 8);
    *(u16x8*)(As + mr * 264 + ch * 8) = *(const u16x8*)src;
  }
  __syncthreads();

  const int ln = lane & 15, quad = lane >> 4;
  const int nq = wave * 32;
  f32x4 acc[4][2];
  #pragma unroll
  for (int i = 0; i < 4; i++)
    #pragma unroll
    for (int j = 0; j < 2; j++)
      acc[i][j] = (f32x4){0.f, 0.f, 0.f, 0.f};

  #pragma unroll
  for (int ks = 0; ks < 8; ks++) {
    bf16x8 af[4], bfr[2];
    #pragma unroll
    for (int i = 0; i < 4; i++)
      af[i] = *(const bf16x8*)(As + (i * 16 + ln) * 264 + ks * 32 + quad * 8);
    #pragma unroll
    for (int j = 0; j < 2; j++)
      bfr[j] = *(const bf16x8*)(weff + (size_t)(nq + j * 16 + ln) * FEAT +
                                ks * 32 + quad * 8);
    #pragma unroll
    for (int i = 0; i < 4; i++)
      #pragma unroll
      for (int j = 0; j < 2; j++)
        acc[i][j] = mfma16(af[i], bfr[j], acc[i][j]);
  }

  #pragma unroll
  for (int j = 0; j < 2; j++) {
    const int gn = nq + j * 16 + ln;
    const float bb = beff[gn];
    #pragma unroll
    for (int i = 0; i < 4; i++) {
      #pragma unroll
      for (int r = 0; r < 4; r++) {
        const int gm = m0 + i * 16 + quad * 4 + r;
        float v = acc[i][j][r] + bb;
        const size_t idx = (size_t)gm * DIM + gn;
        if (mode == 0) {
          v = v > 0.f ? v : expm1f(v);
          ((unsigned short*)outv)[idx] = f2bf(v);
        } else {
          v += bf2f(resid[idx]);
          if (is32) ((float*)outv)[idx] = v;
          else      ((unsigned short*)outv)[idx] = f2bf(v);
        }
      }
    }
  }
}

// ---------------------------------------------------------------------------
extern "C" void kernel_launch(void* const* d_in, const int* in_sizes, int n_in,
                              void* d_out, int out_size, void* d_ws, size_t ws_size,
                              hipStream_t stream) {
  const void* Lm   = d_in[0];
  // d_in[1] = mask (unused)
  const void* inp  = d_in[2];
  const void* bn0g = d_in[3];
  const void* bn0b = d_in[4];
  const void* fc0w = d_in[5];
  const void* fc0b = d_in[6];
  const void* bn1g = d_in[7];
  const void* bn1b = d_in[8];
  const void* fc1w = d_in[9];
  const void* fc1b = d_in[10];

  char* ws = (char*)d_ws;
  unsigned short* x0   = (unsigned short*)(ws);               // 2 MB
  unsigned short* xT   = (unsigned short*)(ws + (2  << 20));  // 2 MB
  float*          Lx   = (float*)         (ws + (4  << 20));  // 4 MB
  unsigned short* Lxb  = (unsigned short*)(ws + (8  << 20));  // 2 MB
  unsigned short* x1   = (unsigned short*)(ws + (10 << 20));  // 2 MB
  float*          stats= (float*)         (ws + (12 << 20));  // 2 KB
  int*            flag = (int*)           (ws + (12 << 20) + 2048);
  float*          beff = (float*)         (ws + (12 << 20) + 4096);
  unsigned short* weff = (unsigned short*)(ws + (12 << 20) + 8192);  // 64 KB
  unsigned short* inpc = (unsigned short*)(ws + (12 << 20) + 8192 + 65536); // 2MB
  unsigned short* pc   = (unsigned short*)(ws + (14 << 20) + 8192 + 65536); // 131KB

  detect_kernel<<<1, 256, 0, stream>>>((const unsigned short*)Lm, flag);
  cvt_tensor<<<1024, 256, 0, stream>>>(inp, inpc, NROWS * DIM, flag);
  cvt_params<<<32, 256, 0, stream>>>(bn0g, bn0b, fc0w, fc0b,
                                     bn1g, bn1b, fc1w, fc1b, pc, flag);

  // ---- block 0 ----
  hipMemsetAsync(stats, 0, 512 * sizeof(float), stream);
  hipMemsetAsync(Lx, 0, (size_t)NROWS * DIM * sizeof(float), stream);
  trans_kernel<<<64, 256, 0, stream>>>(inpc, xT, x0, 1);
  colstats_x<<<128, 128, 0, stream>>>(x0, stats);
  gemm1_splitk<<<dim3(64, KSPLIT), 256, 0, stream>>>(Lm, xT, Lx, flag);
  lx_stats<<<128, 128, 0, stream>>>(Lx, Lxb, stats);
  prep_kernel<<<128, 256, 0, stream>>>(stats, pc + 0, pc + 256, pc + 512,
                                       pc + 33280, weff, beff);
  gemm2_fc<<<128, 256, 0, stream>>>(x0, Lxb, weff, beff, nullptr, x1, 0, flag);

  // ---- block 1 ----
  hipMemsetAsync(stats, 0, 512 * sizeof(float), stream);
  hipMemsetAsync(Lx, 0, (size_t)NROWS * DIM * sizeof(float), stream);
  trans_kernel<<<64, 256, 0, stream>>>(x1, xT, nullptr, 0);
  colstats_x<<<128, 128, 0, stream>>>(x1, stats);
  gemm1_splitk<<<dim3(64, KSPLIT), 256, 0, stream>>>(Lm, xT, Lx, flag);
  lx_stats<<<128, 128, 0, stream>>>(Lx, Lxb, stats);
  prep_kernel<<<128, 256, 0, stream>>>(stats, pc + 33408, pc + 33664,
                                       pc + 33920, pc + 66688, weff, beff);
  gemm2_fc<<<128, 256, 0, stream>>>(x1, Lxb, weff, beff, inpc, d_out, 1, flag);
}

// Round 3
// 566.388 us; speedup vs baseline: 1.0775x; 1.0775x over previous
//
#include <hip/hip_runtime.h>
#include <math.h>

#define NROWS 8192   // BATCH*NODE
#define DIM   128
#define FEAT  256
#define KSPLIT 8
#define KCH   (NROWS / KSPLIT)  // 1024

typedef __attribute__((ext_vector_type(8))) __bf16 bf16x8;
typedef __attribute__((ext_vector_type(8))) unsigned short u16x8;
typedef __attribute__((ext_vector_type(4))) unsigned short u16x4;
typedef __attribute__((ext_vector_type(4))) float f32x4;

__device__ __forceinline__ float bf2f(unsigned short h) {
  return __uint_as_float(((unsigned)h) << 16);
}
__device__ __forceinline__ unsigned short f2bf(float f) {
  unsigned u = __float_as_uint(f);
  return (unsigned short)((u + 0x7fff + ((u >> 16) & 1)) >> 16);  // RNE
}
__device__ __forceinline__ void async16(const void* g, void* l) {
  __builtin_amdgcn_global_load_lds(
      (const __attribute__((address_space(1))) void*)g,
      (__attribute__((address_space(3))) void*)l, 16, 0, 0);
}
__device__ __forceinline__ f32x4 mfma16(bf16x8 a, bf16x8 b, f32x4 c) {
  return __builtin_amdgcn_mfma_f32_16x16x32_bf16(a, b, c, 0, 0, 0);
}

// ---------------------------------------------------------------------------
// dtype detection (f32 L: even shorts are uniform mantissa bits -> ~25% have
// bf16-exponent >= 192; bf16 L: |v|<=0.07 -> exponent < 123 -> count 0)
// ---------------------------------------------------------------------------
__global__ void detect_kernel(const unsigned short* __restrict__ L,
                              int* __restrict__ flag)
{
  __shared__ int cnt;
  if (threadIdx.x == 0) cnt = 0;
  __syncthreads();
  int c = 0;
  for (int i = 0; i < 64; i++) {
    unsigned short s = L[2 * (threadIdx.x + 256 * i)];
    int e = (s >> 7) & 0xFF;
    if (e >= 192) c++;
  }
  atomicAdd(&cnt, c);
  __syncthreads();
  if (threadIdx.x == 0) *flag = (cnt > 16) ? 1 : 0;
}

// ---------------------------------------------------------------------------
// L (f32 or bf16) -> Lb bf16, 8 elements/thread/iter
// ---------------------------------------------------------------------------
__global__ __launch_bounds__(256) void cvt_L(const void* __restrict__ src,
                                             unsigned short* __restrict__ dst,
                                             const int* __restrict__ flag)
{
  const int is32 = *flag;
  const size_t n = (size_t)NROWS * NROWS;  // 64M
  size_t i = ((size_t)blockIdx.x * 256 + threadIdx.x) * 8;
  const size_t stride = (size_t)gridDim.x * 256 * 8;
  for (; i < n; i += stride) {
    u16x8 o;
    if (is32) {
      const float* s = (const float*)src + i;
      f32x4 a = *(const f32x4*)s, b = *(const f32x4*)(s + 4);
      #pragma unroll
      for (int e = 0; e < 4; e++) { o[e] = f2bf(a[e]); o[e + 4] = f2bf(b[e]); }
    } else {
      o = *(const u16x8*)((const unsigned short*)src + i);
    }
    *(u16x8*)(dst + i) = o;
  }
}

// ---------------------------------------------------------------------------
// copy-or-convert small tensors to bf16
// ---------------------------------------------------------------------------
__global__ void cvt_tensor(const void* __restrict__ src,
                           unsigned short* __restrict__ dst, int n,
                           const int* __restrict__ flag)
{
  const int is32 = *flag;
  for (int i = blockIdx.x * 256 + threadIdx.x; i < n; i += gridDim.x * 256)
    dst[i] = is32 ? f2bf(((const float*)src)[i])
                  : ((const unsigned short*)src)[i];
}

// params: g0[256] b0[256] w0[32768] bi0[128] g1[256] b1[256] w1[32768] bi1[128]
__global__ void cvt_params(const void* g0, const void* b0, const void* w0,
                           const void* bi0, const void* g1, const void* b1,
                           const void* w1, const void* bi1,
                           unsigned short* __restrict__ dst,
                           const int* __restrict__ flag)
{
  const int is32 = *flag;
  for (int i = blockIdx.x * 256 + threadIdx.x; i < 66816; i += gridDim.x * 256) {
    const void* src; int off;
    if      (i < 256)   { src = g0;  off = i; }
    else if (i < 512)   { src = b0;  off = i - 256; }
    else if (i < 33280) { src = w0;  off = i - 512; }
    else if (i < 33408) { src = bi0; off = i - 33280; }
    else if (i < 33664) { src = g1;  off = i - 33408; }
    else if (i < 33920) { src = b1;  off = i - 33664; }
    else if (i < 66688) { src = w1;  off = i - 33920; }
    else                { src = bi1; off = i - 66688; }
    dst[i] = is32 ? f2bf(((const float*)src)[off])
                  : ((const unsigned short*)src)[off];
  }
}

// ---------------------------------------------------------------------------
// elu(optional) + transpose: src (8192x128 bf16) -> xT (128x8192), xcopy
// ---------------------------------------------------------------------------
__global__ __launch_bounds__(256) void trans_kernel(
    const unsigned short* __restrict__ src, unsigned short* __restrict__ xT,
    unsigned short* __restrict__ xcopy, int do_elu)
{
  __shared__ __align__(16) unsigned short T[128 * 136];  // pad 128->136
  const int tid = threadIdx.x;
  const int r0 = blockIdx.x * 128;
  #pragma unroll
  for (int i = 0; i < 8; i++) {
    const int c = tid + 256 * i;           // 0..2047
    const int rr = c >> 4, cg = c & 15;
    u16x8 v = *(const u16x8*)(src + (size_t)(r0 + rr) * DIM + cg * 8);
    if (do_elu) {
      #pragma unroll
      for (int e = 0; e < 8; e++) {
        float f = bf2f(v[e]);
        f = f > 0.f ? f : expm1f(f);
        v[e] = f2bf(f);
      }
      *(u16x8*)(xcopy + (size_t)(r0 + rr) * DIM + cg * 8) = v;
    }
    *(u16x8*)(T + rr * 136 + cg * 8) = v;
  }
  __syncthreads();
  #pragma unroll
  for (int i = 0; i < 8; i++) {
    const int c = tid + 256 * i;
    const int n = c >> 4, mg = c & 15;
    u16x8 v;
    #pragma unroll
    for (int e = 0; e < 8; e++) v[e] = T[(mg * 8 + e) * 136 + n];
    *(u16x8*)(xT + (size_t)n * NROWS + r0 + mg * 8) = v;
  }
}

// ---------------------------------------------------------------------------
// column stats of bf16 x (features 0..127)
// ---------------------------------------------------------------------------
__global__ void colstats_x(const unsigned short* __restrict__ x,
                           float* __restrict__ stats)
{
  const int col = threadIdx.x;          // 0..127
  const int r0 = blockIdx.x * 64;
  float s = 0.f, q = 0.f;
  for (int i = 0; i < 64; i++) {
    float v = bf2f(x[(size_t)(r0 + i) * DIM + col]);
    s += v; q += v * v;
  }
  atomicAdd(&stats[col], s);
  atomicAdd(&stats[256 + col], q);
}

// ---------------------------------------------------------------------------
// reduce KSPLIT partials -> Lxb bf16 + column stats (features 128..255)
// ---------------------------------------------------------------------------
__global__ void lx_reduce(const float* __restrict__ Lxp,
                          unsigned short* __restrict__ Lxb,
                          float* __restrict__ stats)
{
  const int col = threadIdx.x;          // 0..127
  const int r0 = blockIdx.x * 64;
  float s = 0.f, q = 0.f;
  for (int i = 0; i < 64; i++) {
    const size_t base = (size_t)(r0 + i) * DIM + col;
    float v = 0.f;
    #pragma unroll
    for (int z = 0; z < KSPLIT; z++)
      v += Lxp[(size_t)z * (NROWS * DIM) + base];
    Lxb[base] = f2bf(v);
    s += v; q += v * v;
  }
  atomicAdd(&stats[128 + col], s);
  atomicAdd(&stats[384 + col], q);
}

// ---------------------------------------------------------------------------
// fold BN into FC
// ---------------------------------------------------------------------------
__global__ void prep_kernel(const float* __restrict__ stats,
                            const unsigned short* __restrict__ gamma,
                            const unsigned short* __restrict__ beta,
                            const unsigned short* __restrict__ w,
                            const unsigned short* __restrict__ bias,
                            unsigned short* __restrict__ weff,
                            float* __restrict__ beff)
{
  const int k = blockIdx.x;   // 0..127
  const int j = threadIdx.x;  // 0..255
  const float inv = 1.f / 8192.f;
  float mu = stats[j] * inv;
  float var = fmaxf(stats[256 + j] * inv - mu * mu, 0.f);
  float s = bf2f(gamma[j]) * rsqrtf(var + 1e-5f);
  float wv = bf2f(w[(size_t)k * FEAT + j]);
  weff[(size_t)k * FEAT + j] = f2bf(wv * s);
  float term = (bf2f(beta[j]) - mu * s) * wv;
  __shared__ float red[256];
  red[j] = term;
  __syncthreads();
  for (int off = 128; off > 0; off >>= 1) {
    if (j < off) red[j] += red[j + off];
    __syncthreads();
  }
  if (j == 0) beff[k] = bf2f(bias[k]) + red[0];
}

// ---------------------------------------------------------------------------
// GEMM1 (split-K, bf16): Lxp[z] = Lb[m0:+128, k0:+1024] @ xT[:, k0:+1024]^T
// global_load_lds width-16 staging; XOR swizzle on k-group so the wave's
// b128 frag reads have bijective start-bank spread per 8 consecutive lanes.
// ---------------------------------------------------------------------------
__global__ __launch_bounds__(256) void gemm1_splitk(
    const unsigned short* __restrict__ Lb,   // 8192 x 8192 bf16
    const unsigned short* __restrict__ xT,   // 128 x 8192 bf16
    float* __restrict__ Lxp)                 // KSPLIT x 8192 x 128 f32
{
  __shared__ __align__(16) unsigned short As[128 * 32];
  __shared__ __align__(16) unsigned short Bs[128 * 32];
  const int tid  = threadIdx.x;
  const int lane = tid & 63;
  const int wave = tid >> 6;
  const int m0 = blockIdx.x * 128;
  const int k0 = blockIdx.y * KCH;

  // staging: 512 16B chunks per tile; wave stages chunks c0 and c0+64.
  // chunk c holds (row = c>>2, lds-slot = c&3); data loaded into slot s is
  // global k-group s ^ ((row>>1)&3).
  const int c0 = wave * 128 + lane;
  const int c1 = c0 + 64;
  const int r0s = c0 >> 2, kg0 = (c0 & 3) ^ ((r0s >> 1) & 3);
  const int r1s = c1 >> 2, kg1 = (c1 & 3) ^ ((r1s >> 1) & 3);
  const unsigned short* gA0 = Lb + (size_t)(m0 + r0s) * NROWS + k0 + kg0 * 8;
  const unsigned short* gA1 = Lb + (size_t)(m0 + r1s) * NROWS + k0 + kg1 * 8;
  const unsigned short* gB0 = xT + (size_t)r0s * NROWS + k0 + kg0 * 8;
  const unsigned short* gB1 = xT + (size_t)r1s * NROWS + k0 + kg1 * 8;
  unsigned short* lA0 = As + wave * 1024;
  unsigned short* lA1 = As + wave * 1024 + 512;
  unsigned short* lB0 = Bs + wave * 1024;
  unsigned short* lB1 = Bs + wave * 1024 + 512;

  const int ln = lane & 15, quad = lane >> 4;
  const int mq = (wave & 1) * 64, nq = (wave >> 1) * 64;
  const int akg = quad ^ ((ln >> 1) & 3);  // slot holding k-group `quad`

  f32x4 acc[4][4];
  #pragma unroll
  for (int i = 0; i < 4; i++)
    #pragma unroll
    for (int j = 0; j < 4; j++)
      acc[i][j] = (f32x4){0.f, 0.f, 0.f, 0.f};

  for (int kb = 0; kb < KCH / 32; ++kb) {
    async16(gA0, lA0); async16(gA1, lA1);
    async16(gB0, lB0); async16(gB1, lB1);
    gA0 += 32; gA1 += 32; gB0 += 32; gB1 += 32;
    __syncthreads();  // drains vmcnt -> LDS valid
    bf16x8 af[4], bfr[4];
    #pragma unroll
    for (int i = 0; i < 4; i++)
      af[i] = *(const bf16x8*)(As + (mq + i * 16 + ln) * 32 + akg * 8);
    #pragma unroll
    for (int j = 0; j < 4; j++)
      bfr[j] = *(const bf16x8*)(Bs + (nq + j * 16 + ln) * 32 + akg * 8);
    #pragma unroll
    for (int i = 0; i < 4; i++)
      #pragma unroll
      for (int j = 0; j < 4; j++)
        acc[i][j] = mfma16(af[i], bfr[j], acc[i][j]);
    __syncthreads();
  }

  // plain stores into this split's private partial buffer
  float* dst = Lxp + (size_t)blockIdx.y * (NROWS * DIM);
  #pragma unroll
  for (int i = 0; i < 4; i++) {
    const int gmb = m0 + mq + i * 16 + quad * 4;
    #pragma unroll
    for (int j = 0; j < 4; j++) {
      const int gn = nq + j * 16 + ln;
      #pragma unroll
      for (int r = 0; r < 4; r++)
        dst[(size_t)(gmb + r) * DIM + gn] = acc[i][j][r];
    }
  }
}

// ---------------------------------------------------------------------------
// GEMM2: out = [x | Lxb] @ weff.T + beff ; mode0: elu->bf16 x1
// mode1: + resid -> d_out (bf16 or f32 per flag). M-tile 32, grid 256.
// ---------------------------------------------------------------------------
__global__ __launch_bounds__(256) void gemm2_fc(
    const unsigned short* __restrict__ xb,    // 8192x128
    const unsigned short* __restrict__ Lxb,   // 8192x128
    const unsigned short* __restrict__ weff,  // 128x256
    const float* __restrict__ beff,           // 128
    const unsigned short* __restrict__ resid, // inp_c (mode1) or nullptr
    void* __restrict__ outv,
    int mode, const int* __restrict__ flag)
{
  __shared__ __align__(16) unsigned short As[32 * 264];
  const int is32 = *flag;
  const int tid = threadIdx.x;
  const int lane = tid & 63, wave = tid >> 6;
  const int m0 = blockIdx.x * 32;

  #pragma unroll
  for (int i = 0; i < 4; i++) {
    const int c = tid + 256 * i;        // 0..1023 (32 rows x 32 chunks)
    const int mr = c >> 5, ch = c & 31;
    const unsigned short* src =
        (ch < 16) ? (xb  + (size_t)(m0 + mr) * DIM + ch * 8)
                  : (Lxb + (size_t)(m0 + mr) * DIM + (ch - 16) * 8);
    *(u16x8*)(As + mr * 264 + ch * 8) = *(const u16x8*)src;
  }
  __syncthreads();

  const int ln = lane & 15, quad = lane >> 4;
  const int nq = wave * 32;
  f32x4 acc[2][2];
  #pragma unroll
  for (int i = 0; i < 2; i++)
    #pragma unroll
    for (int j = 0; j < 2; j++)
      acc[i][j] = (f32x4){0.f, 0.f, 0.f, 0.f};

  #pragma unroll
  for (int ks = 0; ks < 8; ks++) {
    bf16x8 af[2], bfr[2];
    #pragma unroll
    for (int i = 0; i < 2; i++)
      af[i] = *(const bf16x8*)(As + (i * 16 + ln) * 264 + ks * 32 + quad * 8);
    #pragma unroll
    for (int j = 0; j < 2; j++)
      bfr[j] = *(const bf16x8*)(weff + (size_t)(nq + j * 16 + ln) * FEAT +
                                ks * 32 + quad * 8);
    #pragma unroll
    for (int i = 0; i < 2; i++)
      #pragma unroll
      for (int j = 0; j < 2; j++)
        acc[i][j] = mfma16(af[i], bfr[j], acc[i][j]);
  }

  #pragma unroll
  for (int j = 0; j < 2; j++) {
    const int gn = nq + j * 16 + ln;
    const float bb = beff[gn];
    #pragma unroll
    for (int i = 0; i < 2; i++) {
      #pragma unroll
      for (int r = 0; r < 4; r++) {
        const int gm = m0 + i * 16 + quad * 4 + r;
        float v = acc[i][j][r] + bb;
        const size_t idx = (size_t)gm * DIM + gn;
        if (mode == 0) {
          v = v > 0.f ? v : expm1f(v);
          ((unsigned short*)outv)[idx] = f2bf(v);
        } else {
          v += bf2f(resid[idx]);
          if (is32) ((float*)outv)[idx] = v;
          else      ((unsigned short*)outv)[idx] = f2bf(v);
        }
      }
    }
  }
}

// ---------------------------------------------------------------------------
extern "C" void kernel_launch(void* const* d_in, const int* in_sizes, int n_in,
                              void* d_out, int out_size, void* d_ws, size_t ws_size,
                              hipStream_t stream) {
  const void* Lm   = d_in[0];
  // d_in[1] = mask (unused)
  const void* inp  = d_in[2];
  const void* bn0g = d_in[3];
  const void* bn0b = d_in[4];
  const void* fc0w = d_in[5];
  const void* fc0b = d_in[6];
  const void* bn1g = d_in[7];
  const void* bn1b = d_in[8];
  const void* fc1w = d_in[9];
  const void* fc1b = d_in[10];

  char* ws = (char*)d_ws;
  unsigned short* Lb   = (unsigned short*)(ws);                      // 128 MB
  unsigned short* x0   = (unsigned short*)(ws + (128ull << 20));     // 2 MB
  unsigned short* xT   = (unsigned short*)(ws + (130ull << 20));     // 2 MB
  float*          Lxp  = (float*)         (ws + (132ull << 20));     // 32 MB
  unsigned short* Lxb  = (unsigned short*)(ws + (164ull << 20));     // 2 MB
  unsigned short* x1   = (unsigned short*)(ws + (166ull << 20));     // 2 MB
  unsigned short* inpc = (unsigned short*)(ws + (168ull << 20));     // 2 MB
  float*          stats= (float*)         (ws + (170ull << 20));     // 2 KB
  int*            flag = (int*)           (ws + (170ull << 20) + 4096);
  float*          beff = (float*)         (ws + (170ull << 20) + 8192);
  unsigned short* weff = (unsigned short*)(ws + (170ull << 20) + 16384); // 64KB
  unsigned short* pc   = (unsigned short*)(ws + (170ull << 20) + 16384 + 65536);

  detect_kernel<<<1, 256, 0, stream>>>((const unsigned short*)Lm, flag);
  cvt_L<<<1024, 256, 0, stream>>>(Lm, Lb, flag);
  cvt_tensor<<<1024, 256, 0, stream>>>(inp, inpc, NROWS * DIM, flag);
  cvt_params<<<32, 256, 0, stream>>>(bn0g, bn0b, fc0w, fc0b,
                                     bn1g, bn1b, fc1w, fc1b, pc, flag);

  // ---- block 0 ----
  hipMemsetAsync(stats, 0, 512 * sizeof(float), stream);
  trans_kernel<<<64, 256, 0, stream>>>(inpc, xT, x0, 1);
  colstats_x<<<128, 128, 0, stream>>>(x0, stats);
  gemm1_splitk<<<dim3(64, KSPLIT), 256, 0, stream>>>(Lb, xT, Lxp);
  lx_reduce<<<128, 128, 0, stream>>>(Lxp, Lxb, stats);
  prep_kernel<<<128, 256, 0, stream>>>(stats, pc + 0, pc + 256, pc + 512,
                                       pc + 33280, weff, beff);
  gemm2_fc<<<256, 256, 0, stream>>>(x0, Lxb, weff, beff, nullptr, x1, 0, flag);

  // ---- block 1 ----
  hipMemsetAsync(stats, 0, 512 * sizeof(float), stream);
  trans_kernel<<<64, 256, 0, stream>>>(x1, xT, nullptr, 0);
  colstats_x<<<128, 128, 0, stream>>>(x1, stats);
  gemm1_splitk<<<dim3(64, KSPLIT), 256, 0, stream>>>(Lb, xT, Lxp);
  lx_reduce<<<128, 128, 0, stream>>>(Lxp, Lxb, stats);
  prep_kernel<<<128, 256, 0, stream>>>(stats, pc + 33408, pc + 33664,
                                       pc + 33920, pc + 66688, weff, beff);
  gemm2_fc<<<256, 256, 0, stream>>>(x1, Lxb, weff, beff, inpc, d_out, 1, flag);
}